// Round 1
// baseline (256.954 us; speedup 1.0000x reference)
//
#include <hip/hip_runtime.h>
#include <hip/hip_bf16.h>

#define SEQ 1024
#define DIM 128
#define NEG_SLOPE 0.1f

typedef __bf16 bf16x8 __attribute__((ext_vector_type(8)));
typedef float f32x4v __attribute__((ext_vector_type(4)));
typedef unsigned short ushort8 __attribute__((ext_vector_type(8)));

// Fused GCN layer:
//   poolsum[i,d] = sum_o mask[o,i]*nodes[o,d]   (MFMA bf16, K=1024)
//   counts[i]    = sum_o mask[o,i]              (exact int VALU)
//   out = leakyrelu(nodes@B + (poolsum/max(counts,1))@W)
// Block: 256 thr (4 waves, 2x2 wave grid), tile 64(i) x 128(d). Grid 512 = 32 batch x 16 mtile.
__global__ __launch_bounds__(256, 2)
void gcn_fused(const float* __restrict__ nodes,
               const int* __restrict__ adj,
               const float* __restrict__ W,
               const float* __restrict__ Bm,
               float* __restrict__ out)
{
    __shared__ float inv_lds[64];
    __shared__ __bf16 pooled_lds[64][136];   // +8 pad keeps b128 alignment, breaks bank stride

    // XCD swizzle: all 16 m-tiles of a batch land on one XCD (blockIdx%8 round-robin)
    const int bid   = blockIdx.x;
    const int xcd   = bid & 7;
    const int slot  = bid >> 3;
    const int batch = ((slot >> 4) << 3) | xcd;   // [0,32)
    const int mtile = slot & 15;                  // [0,16)
    const int i0    = mtile << 6;                 // 64-row tile

    const int tid  = threadIdx.x;
    const int wave = tid >> 6;
    const int lane = tid & 63;
    const int wm   = wave >> 1;   // 0..1 -> i-half
    const int wn   = wave & 1;    // 0..1 -> d-half
    const int lrow = lane & 15;
    const int quad = lane >> 4;

    const int*   __restrict__ adj_b   = adj   + (size_t)batch * SEQ * SEQ;
    const float* __restrict__ nodes_b = nodes + (size_t)batch * SEQ * DIM;

    f32x4v acc[2][4] = {};        // 2 m-frags x 4 n-frags (wave tile 32x64)
    int cnt0 = 0, cnt1 = 0;

    const int i_a0 = i0 + wm * 32 + lrow;   // A-frag i (mf adds +16)
    const int d_b0 = wn * 64 + lrow;        // B-frag d (nf adds +16)

    // A-frag: lane holds mask[k0+quad*8+j][i_a0]; B-frag: nodes[k0+quad*8+j][d_b0]
    const int*   pa = adj_b   + (size_t)(quad * 8) * SEQ + i_a0;
    const float* pb = nodes_b + (size_t)(quad * 8) * DIM + d_b0;

    #pragma unroll 2
    for (int ks = 0; ks < 32; ++ks) {
        ushort8 au0, au1;
        bf16x8  bv[4];
        #pragma unroll
        for (int j = 0; j < 8; ++j) {
            const int x0 = pa[(size_t)j * SEQ];
            const int x1 = pa[(size_t)j * SEQ + 16];
            cnt0 += (x0 != 0);
            cnt1 += (x1 != 0);
            au0[j] = (x0 != 0) ? (unsigned short)0x3F80 : (unsigned short)0;  // bf16 1.0
            au1[j] = (x1 != 0) ? (unsigned short)0x3F80 : (unsigned short)0;
        }
        #pragma unroll
        for (int nf = 0; nf < 4; ++nf) {
            #pragma unroll
            for (int j = 0; j < 8; ++j)
                bv[nf][j] = (__bf16)pb[j * DIM + nf * 16];   // imm-offset loads off one base
        }
        const bf16x8 av0 = __builtin_bit_cast(bf16x8, au0);
        const bf16x8 av1 = __builtin_bit_cast(bf16x8, au1);
        #pragma unroll
        for (int nf = 0; nf < 4; ++nf)
            acc[0][nf] = __builtin_amdgcn_mfma_f32_16x16x32_bf16(av0, bv[nf], acc[0][nf], 0, 0, 0);
        #pragma unroll
        for (int nf = 0; nf < 4; ++nf)
            acc[1][nf] = __builtin_amdgcn_mfma_f32_16x16x32_bf16(av1, bv[nf], acc[1][nf], 0, 0, 0);
        pa += 32 * SEQ;
        pb += 32 * DIM;
    }

    // exact in-degree: reduce partial counts across the 4 quads sharing one i
    {
        int c0 = cnt0;
        c0 += __shfl_xor(c0, 16);
        c0 += __shfl_xor(c0, 32);
        int c1 = cnt1;
        c1 += __shfl_xor(c1, 16);
        c1 += __shfl_xor(c1, 32);
        if (wn == 0 && quad == 0) {
            inv_lds[wm * 32 + lrow]      = (c0 > 0) ? 1.0f / (float)c0 : 0.0f;
            inv_lds[wm * 32 + 16 + lrow] = (c1 > 0) ? 1.0f / (float)c1 : 0.0f;
        }
    }
    __syncthreads();

    // poolsum -> pooled (divide by count), C-layout -> A-layout via LDS
    #pragma unroll
    for (int mf = 0; mf < 2; ++mf) {
        #pragma unroll
        for (int r = 0; r < 4; ++r) {
            const int row = wm * 32 + mf * 16 + quad * 4 + r;   // C row = quad*4+reg
            const float inv = inv_lds[row];
            #pragma unroll
            for (int nf = 0; nf < 4; ++nf) {
                const int col = wn * 64 + nf * 16 + lrow;        // C col = lane&15
                pooled_lds[row][col] = (__bf16)(acc[mf][nf][r] * inv);
            }
        }
    }
    __syncthreads();

    f32x4v acc2[2][4] = {};

    // pooled @ W  (K=128, A from LDS b128 reads, B from global W rows)
    #pragma unroll
    for (int ks = 0; ks < 4; ++ks) {
        const int k0 = ks * 32 + quad * 8;
        bf16x8 av[2];
        #pragma unroll
        for (int mf = 0; mf < 2; ++mf)
            av[mf] = *(const bf16x8*)&pooled_lds[wm * 32 + mf * 16 + lrow][k0];
        bf16x8 bv[4];
        const float* pw = W + (size_t)k0 * DIM + d_b0;
        #pragma unroll
        for (int nf = 0; nf < 4; ++nf) {
            #pragma unroll
            for (int j = 0; j < 8; ++j)
                bv[nf][j] = (__bf16)pw[j * DIM + nf * 16];
        }
        #pragma unroll
        for (int mf = 0; mf < 2; ++mf) {
            #pragma unroll
            for (int nf = 0; nf < 4; ++nf)
                acc2[mf][nf] = __builtin_amdgcn_mfma_f32_16x16x32_bf16(av[mf], bv[nf], acc2[mf][nf], 0, 0, 0);
        }
    }

    // nodes @ B  (K=128, A rows are k-contiguous in global -> float4 loads)
    #pragma unroll
    for (int ks = 0; ks < 4; ++ks) {
        const int k0 = ks * 32 + quad * 8;
        bf16x8 av[2];
        #pragma unroll
        for (int mf = 0; mf < 2; ++mf) {
            const float* p = nodes_b + (size_t)(i0 + wm * 32 + mf * 16 + lrow) * DIM + k0;
            const float4 f1 = *(const float4*)p;
            const float4 f2 = *(const float4*)(p + 4);
            av[mf][0] = (__bf16)f1.x; av[mf][1] = (__bf16)f1.y;
            av[mf][2] = (__bf16)f1.z; av[mf][3] = (__bf16)f1.w;
            av[mf][4] = (__bf16)f2.x; av[mf][5] = (__bf16)f2.y;
            av[mf][6] = (__bf16)f2.z; av[mf][7] = (__bf16)f2.w;
        }
        bf16x8 bv[4];
        const float* pB = Bm + (size_t)k0 * DIM + d_b0;
        #pragma unroll
        for (int nf = 0; nf < 4; ++nf) {
            #pragma unroll
            for (int j = 0; j < 8; ++j)
                bv[nf][j] = (__bf16)pB[j * DIM + nf * 16];
        }
        #pragma unroll
        for (int mf = 0; mf < 2; ++mf) {
            #pragma unroll
            for (int nf = 0; nf < 4; ++nf)
                acc2[mf][nf] = __builtin_amdgcn_mfma_f32_16x16x32_bf16(av[mf], bv[nf], acc2[mf][nf], 0, 0, 0);
        }
    }

    // leaky-relu + store (C layout: row=quad*4+r, col=lane&15)
    float* out_b = out + (size_t)batch * SEQ * DIM;
    #pragma unroll
    for (int mf = 0; mf < 2; ++mf) {
        #pragma unroll
        for (int nf = 0; nf < 4; ++nf) {
            const int col = wn * 64 + nf * 16 + lrow;
            #pragma unroll
            for (int r = 0; r < 4; ++r) {
                const int row = i0 + wm * 32 + mf * 16 + quad * 4 + r;
                const float x = acc2[mf][nf][r];
                out_b[(size_t)row * DIM + col] = (x > 0.0f) ? x : NEG_SLOPE * x;
            }
        }
    }
}

extern "C" void kernel_launch(void* const* d_in, const int* in_sizes, int n_in,
                              void* d_out, int out_size, void* d_ws, size_t ws_size,
                              hipStream_t stream) {
    const float* nodes = (const float*)d_in[0];
    const int*   adj   = (const int*)d_in[1];
    const float* W     = (const float*)d_in[2];
    const float* Bm    = (const float*)d_in[3];
    float*       out   = (float*)d_out;
    gcn_fused<<<dim3(512), dim3(256), 0, stream>>>(nodes, adj, W, Bm, out);
}

// Round 2
// 224.155 us; speedup vs baseline: 1.1463x; 1.1463x over previous
//
#include <hip/hip_runtime.h>
#include <hip/hip_bf16.h>

#define SEQ 1024
#define DIM 128
#define NEG_SLOPE 0.1f

typedef __bf16 bf16x8 __attribute__((ext_vector_type(8)));
typedef float f32x4v __attribute__((ext_vector_type(4)));

// LDS: staging buffers (phase 1) unioned with pooled matrix (phase 2).
// Row strides chosen 16B-aligned (72 u16 = 144 B; 136 u16 = 272 B) so
// ds_read_b128 is legal; 144B stride gives conflict-free b128 frag reads.
union LdsU {
    struct {
        unsigned short mask_t[64][72];    // [i][o] bf16 bits, transposed adj chunk
        unsigned short nodes_t[128][72];  // [d][o] bf16 bits, transposed nodes chunk
    } s;
    unsigned short pooled[64][136];       // [i][d] bf16 bits (phase 2 A operand)
};

__device__ __forceinline__ unsigned short bfb(float f) {
    __bf16 h = (__bf16)f;
    return __builtin_bit_cast(unsigned short, h);
}
__device__ __forceinline__ unsigned mpack(int x0, int x1) {
    unsigned m0 = (x0 != 0) ? 0x3F80u : 0u;   // bf16 1.0
    unsigned m1 = (x1 != 0) ? 0x3F80u : 0u;
    return m0 | (m1 << 16);
}

__global__ __launch_bounds__(256, 2)
void gcn_fused(const float* __restrict__ nodes,
               const int* __restrict__ adj,
               const float* __restrict__ W,
               const float* __restrict__ Bm,
               float* __restrict__ out)
{
    __shared__ LdsU u;

    // XCD swizzle: all 16 m-tiles of a batch land on one XCD
    const int bid   = blockIdx.x;
    const int xcd   = bid & 7;
    const int slot  = bid >> 3;
    const int batch = ((slot >> 4) << 3) | xcd;   // [0,32)
    const int mtile = slot & 15;                  // [0,16)
    const int i0    = mtile << 6;

    const int tid  = threadIdx.x;
    const int wave = tid >> 6;
    const int lane = tid & 63;
    const int wm   = wave >> 1;
    const int wn   = wave & 1;
    const int lrow = lane & 15;
    const int quad = lane >> 4;

    const int*   __restrict__ adj_b   = adj   + (size_t)batch * SEQ * SEQ;
    const float* __restrict__ nodes_b = nodes + (size_t)batch * SEQ * DIM;

    // staging thread mapping
    const int a_row = (tid >> 4) * 4;   // adj o-row group (4 consecutive rows)
    const int a_col = (tid & 15) * 4;   // adj i group (int4)
    const int n_row = (tid >> 5) * 4;   // nodes o-row group
    const int n_col = (tid & 31) * 4;   // nodes d group (float4)

    f32x4v acc[2][4] = {};
    f32x4v acc_cnt[2] = {};

    bf16x8 ones;
    #pragma unroll
    for (int j = 0; j < 8; ++j) ones[j] = __builtin_bit_cast(__bf16, (unsigned short)0x3F80);

    int4   A[4];
    float4 N[8];

    auto load_chunk = [&](int o0) {
        const int* pa = adj_b + (size_t)(o0 + a_row) * SEQ + (i0 + a_col);
        #pragma unroll
        for (int r = 0; r < 4; ++r) A[r] = *(const int4*)(pa + (size_t)r * SEQ);
        const float* pn = nodes_b + (size_t)(o0 + n_row) * DIM + n_col;
        #pragma unroll
        for (int it = 0; it < 2; ++it)
            #pragma unroll
            for (int r = 0; r < 4; ++r)
                N[it * 4 + r] = *(const float4*)(pn + (size_t)(it * 32 + r) * DIM);
    };

    load_chunk(0);

    for (int chunk = 0; chunk < 16; ++chunk) {
        __syncthreads();   // previous chunk's frag reads complete
        // in-register 4x4 transpose -> b64 LDS writes
        #pragma unroll
        for (int j = 0; j < 4; ++j) {
            uint2 w;
            w.x = mpack(((const int*)&A[0])[j], ((const int*)&A[1])[j]);
            w.y = mpack(((const int*)&A[2])[j], ((const int*)&A[3])[j]);
            *(uint2*)&u.s.mask_t[a_col + j][a_row] = w;
        }
        #pragma unroll
        for (int it = 0; it < 2; ++it) {
            #pragma unroll
            for (int j = 0; j < 4; ++j) {
                uint2 w;
                w.x = (unsigned)bfb(((const float*)&N[it*4+0])[j]) |
                      ((unsigned)bfb(((const float*)&N[it*4+1])[j]) << 16);
                w.y = (unsigned)bfb(((const float*)&N[it*4+2])[j]) |
                      ((unsigned)bfb(((const float*)&N[it*4+3])[j]) << 16);
                *(uint2*)&u.s.nodes_t[n_col + j][it * 32 + n_row] = w;
            }
        }
        __syncthreads();
        if (chunk < 15) load_chunk((chunk + 1) * 64);   // prefetch overlaps compute

        #pragma unroll
        for (int kk = 0; kk < 2; ++kk) {
            bf16x8 av[2], bv[4];
            av[0] = *(const bf16x8*)&u.s.mask_t[wm * 32 + lrow][kk * 32 + quad * 8];
            av[1] = *(const bf16x8*)&u.s.mask_t[wm * 32 + 16 + lrow][kk * 32 + quad * 8];
            #pragma unroll
            for (int nf = 0; nf < 4; ++nf)
                bv[nf] = *(const bf16x8*)&u.s.nodes_t[wn * 64 + nf * 16 + lrow][kk * 32 + quad * 8];
            #pragma unroll
            for (int mf = 0; mf < 2; ++mf) {
                #pragma unroll
                for (int nf = 0; nf < 4; ++nf)
                    acc[mf][nf] = __builtin_amdgcn_mfma_f32_16x16x32_bf16(av[mf], bv[nf], acc[mf][nf], 0, 0, 0);
                acc_cnt[mf] = __builtin_amdgcn_mfma_f32_16x16x32_bf16(av[mf], ones, acc_cnt[mf], 0, 0, 0);
            }
        }
    }

    // poolsum -> pooled (divide by exact MFMA-computed in-degree), C-layout -> A-layout via LDS
    __syncthreads();
    #pragma unroll
    for (int mf = 0; mf < 2; ++mf) {
        #pragma unroll
        for (int r = 0; r < 4; ++r) {
            const int row = wm * 32 + mf * 16 + quad * 4 + r;
            const float cnt = acc_cnt[mf][r];           // all columns equal = row count
            const float inv = (cnt > 0.5f) ? 1.0f / cnt : 0.0f;
            #pragma unroll
            for (int nf = 0; nf < 4; ++nf) {
                const int col = wn * 64 + nf * 16 + lrow;
                u.pooled[row][col] = bfb(acc[mf][nf][r] * inv);
            }
        }
    }
    __syncthreads();

    f32x4v acc2[2][4] = {};
    const int d_b0 = wn * 64 + lrow;

    // pooled @ W  (K=128)
    #pragma unroll
    for (int ks = 0; ks < 4; ++ks) {
        const int k0 = ks * 32 + quad * 8;
        bf16x8 av[2];
        #pragma unroll
        for (int mf = 0; mf < 2; ++mf)
            av[mf] = *(const bf16x8*)&u.pooled[wm * 32 + mf * 16 + lrow][k0];
        bf16x8 bv[4];
        const float* pw = W + (size_t)k0 * DIM + d_b0;
        #pragma unroll
        for (int nf = 0; nf < 4; ++nf) {
            #pragma unroll
            for (int j = 0; j < 8; ++j)
                bv[nf][j] = (__bf16)pw[j * DIM + nf * 16];
        }
        #pragma unroll
        for (int mf = 0; mf < 2; ++mf)
            #pragma unroll
            for (int nf = 0; nf < 4; ++nf)
                acc2[mf][nf] = __builtin_amdgcn_mfma_f32_16x16x32_bf16(av[mf], bv[nf], acc2[mf][nf], 0, 0, 0);
    }

    // nodes @ B  (K=128)
    #pragma unroll
    for (int ks = 0; ks < 4; ++ks) {
        const int k0 = ks * 32 + quad * 8;
        bf16x8 av[2];
        #pragma unroll
        for (int mf = 0; mf < 2; ++mf) {
            const float* p = nodes_b + (size_t)(i0 + wm * 32 + mf * 16 + lrow) * DIM + k0;
            const float4 f1 = *(const float4*)p;
            const float4 f2 = *(const float4*)(p + 4);
            av[mf][0] = (__bf16)f1.x; av[mf][1] = (__bf16)f1.y;
            av[mf][2] = (__bf16)f1.z; av[mf][3] = (__bf16)f1.w;
            av[mf][4] = (__bf16)f2.x; av[mf][5] = (__bf16)f2.y;
            av[mf][6] = (__bf16)f2.z; av[mf][7] = (__bf16)f2.w;
        }
        bf16x8 bv[4];
        const float* pB = Bm + (size_t)k0 * DIM + d_b0;
        #pragma unroll
        for (int nf = 0; nf < 4; ++nf) {
            #pragma unroll
            for (int j = 0; j < 8; ++j)
                bv[nf][j] = (__bf16)pB[j * DIM + nf * 16];
        }
        #pragma unroll
        for (int mf = 0; mf < 2; ++mf)
            #pragma unroll
            for (int nf = 0; nf < 4; ++nf)
                acc2[mf][nf] = __builtin_amdgcn_mfma_f32_16x16x32_bf16(av[mf], bv[nf], acc2[mf][nf], 0, 0, 0);
    }

    // leaky-relu + store
    float* out_b = out + (size_t)batch * SEQ * DIM;
    #pragma unroll
    for (int mf = 0; mf < 2; ++mf) {
        #pragma unroll
        for (int nf = 0; nf < 4; ++nf) {
            const int col = wn * 64 + nf * 16 + lrow;
            #pragma unroll
            for (int r = 0; r < 4; ++r) {
                const int row = i0 + wm * 32 + mf * 16 + quad * 4 + r;
                const float x = acc2[mf][nf][r];
                out_b[(size_t)row * DIM + col] = (x > 0.0f) ? x : NEG_SLOPE * x;
            }
        }
    }
}

extern "C" void kernel_launch(void* const* d_in, const int* in_sizes, int n_in,
                              void* d_out, int out_size, void* d_ws, size_t ws_size,
                              hipStream_t stream) {
    const float* nodes = (const float*)d_in[0];
    const int*   adj   = (const int*)d_in[1];
    const float* W     = (const float*)d_in[2];
    const float* Bm    = (const float*)d_in[3];
    float*       out   = (float*)d_out;
    gcn_fused<<<dim3(512), dim3(256), 0, stream>>>(nodes, adj, W, Bm, out);
}